// Round 5
// baseline (6721.982 us; speedup 1.0000x reference)
//
#include <hip/hip_runtime.h>

#define S_LEN 1024
#define BATCH 64
#define I_DIM 256
#define H_DIM 512
#define NCL 8      // clusters (8 batch rows each) — one XCD per cluster in fast path
#define NRK 8      // WGs per cluster (64 feats each)
#define ROWS 8
#define FPW 64     // feats per WG (16 per wave, full K per wave)
#define HSTR 520   // LDS row stride (bf16 elems) for h
#define XSTR 264   // LDS row stride (bf16) for x staging in precompute
#define POLL_CAP 16384
#define HSHAKE_CAP 200000
#define TRIAL_CAP 30000

typedef short short8 __attribute__((ext_vector_type(8)));
typedef float floatx4 __attribute__((ext_vector_type(4)));
typedef unsigned short ushortx4 __attribute__((ext_vector_type(4)));

__device__ inline unsigned short f2bf(float x){
  unsigned u = __float_as_uint(x);
  u += 0x7fffu + ((u >> 16) & 1u);           // RNE
  return (unsigned short)(u >> 16);
}
__device__ inline float bf2f(unsigned short s){
  return __uint_as_float(((unsigned)s) << 16);
}
__device__ inline float fast_tanh(float x){
  float e = __expf(2.0f * x);                // inf-safe: +inf -> 1, 0 -> -1
  return 1.0f - 2.0f / (e + 1.0f);
}
__device__ inline float fast_sigmoid(float x){
  return 1.0f / (1.0f + __expf(-x));
}
__device__ inline short8 cvt8(const float* p){
  short8 r;
#pragma unroll
  for (int j = 0; j < 8; j++) r[j] = (short)f2bf(p[j]);
  return r;
}

// ---- scoped comm primitives ------------------------------------------------
// fast (same-XCD cluster): plain stores land in the XCD's L2 (L1 is read-only
// on CDNA; stores always reach L2). Reads use atomic RMW fetch_add(0) —
// atomics are NEVER served by L1 and, without sc1, execute in the LOCAL L2.
// slow (device): AGENT-scope atomics (round-0/4 verified mechanism).
__device__ inline void comm_st_u32(unsigned* p, unsigned v, bool fast){
  if (fast) __hip_atomic_store(p, v, __ATOMIC_RELAXED, __HIP_MEMORY_SCOPE_WORKGROUP);
  else      __hip_atomic_store(p, v, __ATOMIC_RELAXED, __HIP_MEMORY_SCOPE_AGENT);
}
__device__ inline void comm_st_f32(float* p, float v, bool fast){
  if (fast) __hip_atomic_store(p, v, __ATOMIC_RELAXED, __HIP_MEMORY_SCOPE_WORKGROUP);
  else      __hip_atomic_store(p, v, __ATOMIC_RELAXED, __HIP_MEMORY_SCOPE_AGENT);
}
__device__ inline unsigned comm_ld_u32(unsigned* p, bool fast){
  if (fast) return __hip_atomic_fetch_add(p, 0u, __ATOMIC_RELAXED, __HIP_MEMORY_SCOPE_WORKGROUP);
  else      return __hip_atomic_load(p, __ATOMIC_RELAXED, __HIP_MEMORY_SCOPE_AGENT);
}
__device__ inline unsigned long long comm_ld_u64(unsigned long long* p, bool fast){
  if (fast) return __hip_atomic_fetch_add(p, 0ull, __ATOMIC_RELAXED, __HIP_MEMORY_SCOPE_WORKGROUP);
  else      return __hip_atomic_load(p, __ATOMIC_RELAXED, __HIP_MEMORY_SCOPE_AGENT);
}
__device__ inline float comm_ld_f32(float* p, bool fast){
  if (fast) return __hip_atomic_fetch_add(p, 0.0f, __ATOMIC_RELAXED, __HIP_MEMORY_SCOPE_WORKGROUP);
  else      return __hip_atomic_load(p, __ATOMIC_RELAXED, __HIP_MEMORY_SCOPE_AGENT);
}

// ---------------------------------------------------------------------------
// Kernel W: pre-convert W_in and tau_w1[:, :256] to bf16. (unchanged)
// ---------------------------------------------------------------------------
__global__ __launch_bounds__(256) void convert_weights_kernel(
  const float* __restrict__ W_in, const float* __restrict__ tau_w1,
  unsigned short* __restrict__ Wbf, unsigned short* __restrict__ Tbf)
{
  const int f = blockIdx.x, k = threadIdx.x;
  Wbf[f * I_DIM + k] = f2bf(W_in[(size_t)f * I_DIM + k]);
  Tbf[f * I_DIM + k] = f2bf(tau_w1[(size_t)f * (I_DIM + H_DIM) + k]);
}

// ---------------------------------------------------------------------------
// Kernel P: A_in[t][F][b], A_tau[t][F][b]  (unchanged)
// ---------------------------------------------------------------------------
__global__ __launch_bounds__(256) void precompute_kernel(
  const float* __restrict__ x, const unsigned short* __restrict__ Wbf,
  const unsigned short* __restrict__ Tbf,
  const float* __restrict__ b_in, const float* __restrict__ tau_b1,
  unsigned short* __restrict__ A_in, unsigned short* __restrict__ A_tau)
{
  __shared__ unsigned short xs[BATCH * XSTR];
  const int t = blockIdx.x, tid = threadIdx.x;
  {
    const int br = tid >> 2, pp = tid & 3;
    const float* xrow = x + ((size_t)br * S_LEN + t) * I_DIM + pp * 64;
    unsigned short* drow = xs + br * XSTR + pp * 64;
#pragma unroll
    for (int c = 0; c < 16; c++){
      float4 v = *(const float4*)(xrow + c * 4);
      ushortx4 o; o[0] = f2bf(v.x); o[1] = f2bf(v.y); o[2] = f2bf(v.z); o[3] = f2bf(v.w);
      *(ushortx4*)(drow + c * 4) = o;
    }
  }
  __syncthreads();

  const int w = tid >> 6, l15 = tid & 15, q = (tid & 63) >> 4;
#pragma unroll 1
  for (int fb = 0; fb < 8; fb++){
    const int F = fb * 64 + w * 16 + l15;
    floatx4 accf[4], acct[4];
#pragma unroll
    for (int m = 0; m < 4; m++){ accf[m] = (floatx4){0,0,0,0}; acct[m] = (floatx4){0,0,0,0}; }
#pragma unroll
    for (int kc = 0; kc < 8; kc++){
      const int k0 = kc * 32 + q * 8;
      short8 bw = *(const short8*)&Wbf[F * I_DIM + k0];
      short8 bt = *(const short8*)&Tbf[F * I_DIM + k0];
#pragma unroll
      for (int m = 0; m < 4; m++){
        short8 a = *(const short8*)&xs[(m * 16 + l15) * XSTR + k0];
        accf[m] = __builtin_amdgcn_mfma_f32_16x16x32_bf16(a, bw, accf[m], 0, 0, 0);
        acct[m] = __builtin_amdgcn_mfma_f32_16x16x32_bf16(a, bt, acct[m], 0, 0, 0);
      }
    }
    const float bi = b_in[F], bt1 = tau_b1[F];
#pragma unroll
    for (int m = 0; m < 4; m++){
      ushortx4 pf, pt;
#pragma unroll
      for (int i2 = 0; i2 < 4; i2++){ pf[i2] = f2bf(accf[m][i2] + bi); pt[i2] = f2bf(acct[m][i2] + bt1); }
      const size_t base = ((size_t)t * H_DIM + F) * BATCH + m * 16 + q * 4;
      *(ushortx4*)(A_in + base) = pf;
      *(ushortx4*)(A_tau + base) = pt;
    }
  }
}

// ---------------------------------------------------------------------------
// Kernel S: persistent scan. 64 WGs x 256 thr.
// Formation: group WGs by HW_REG_XCC_ID (multiples of 8 per XCD -> clusters
// are XCD-local). Trial: 2-phase ping-pong on the REAL fast mechanism
// (L2-local store + atomic-RMW read); any timeout -> global demote to the
// AGENT path (round-4 verified). Flag slots padded to 64 B.
// flags layout (u32 idx): [0..1024) step flags (slot<<4) | 1024..1031 initcnt
// | 1040 g_cnt | 1041 g_cnt2 | 1042 demote | [1088..2112) trial (slot<<4).
// ---------------------------------------------------------------------------
__global__ __launch_bounds__(256, 1) void scan_kernel(
  const float* __restrict__ h0, const float* __restrict__ W_rec,
  const float* __restrict__ tau_w1, const float* __restrict__ tau_w2,
  const float* __restrict__ tau_b2_p, const float* __restrict__ gamma,
  const float* __restrict__ beta,
  const unsigned short* __restrict__ A_in, const unsigned short* __restrict__ A_tau,
  unsigned short* __restrict__ bc_f, float* __restrict__ bc_td,
  unsigned int* __restrict__ flags,
  float* __restrict__ out0, float* __restrict__ outh, float* __restrict__ outtau)
{
  __shared__ unsigned short hB[16 * HSTR];   // rows 8..15 stay zero (MFMA M=16 pad)
  __shared__ int sh_cl, sh_rk, sh_fast;

  const int tid = threadIdx.x;

  // ---- phase 1: discover XCD, form clusters (AGENT machinery, verified r3) ----
  if (tid == 0){
    unsigned xcd;
    asm volatile("s_getreg_b32 %0, hwreg(HW_REG_XCC_ID)" : "=s"(xcd));
    xcd &= 7u;
    unsigned* initcnt = flags + 1024;
    unsigned* g_cnt   = flags + 1040;
    int slot = atomicAdd((int*)&initcnt[xcd], 1);
    __builtin_amdgcn_s_waitcnt(0);
    atomicAdd((int*)g_cnt, 1);
    unsigned seen = 0; int hcap = 0;
    for (;;){
      seen = __hip_atomic_load(g_cnt, __ATOMIC_RELAXED, __HIP_MEMORY_SCOPE_AGENT);
      if (seen >= 64u || ++hcap > HSHAKE_CAP) break;
      __builtin_amdgcn_s_sleep(8);
    }
    int ok = (seen >= 64u) ? 1 : 0;
    unsigned c8[8]; int pre = 0;
#pragma unroll
    for (int x2 = 0; x2 < 8; x2++){
      c8[x2] = __hip_atomic_load(&initcnt[x2], __ATOMIC_RELAXED, __HIP_MEMORY_SCOPE_AGENT);
      ok &= ((c8[x2] & 7u) == 0u);
    }
    for (unsigned y = 0; y < xcd; y++) pre += (int)(c8[y] >> 3);
    if (ok){ sh_cl = pre + (slot >> 3); sh_rk = slot & 7; sh_fast = 1; }
    else {
      sh_cl = (int)(blockIdx.x & 7); sh_rk = (int)(blockIdx.x >> 3); sh_fast = 0;
      __hip_atomic_store(&flags[1042], 1u, __ATOMIC_RELAXED, __HIP_MEMORY_SCOPE_AGENT);
    }
  }
  for (int idx = tid; idx < 16 * HSTR; idx += 256) hB[idx] = 0;
  __syncthreads();
  const int cl = sh_cl, rank = sh_rk;

  // ---- phase 2: 2-phase ping-pong trial of the fast mechanism ----
  if (sh_fast){
    unsigned* T = flags + 1088;
#pragma unroll 1
    for (unsigned ph = 1; ph <= 2; ph++){
      if (tid == 0) comm_st_u32(&T[(cl * 8 + rank) << 4], ph, true);
      __builtin_amdgcn_s_waitcnt(0);
      if (tid < 8){
        int g = 0;
        while (comm_ld_u32(&T[(cl * 8 + tid) << 4], true) < ph){
          if (++g > TRIAL_CAP){
            __hip_atomic_store(&flags[1042], 1u, __ATOMIC_RELAXED, __HIP_MEMORY_SCOPE_AGENT);
            break;
          }
          __builtin_amdgcn_s_sleep(1);
        }
      }
      __syncthreads();
    }
  }
  // ---- phase 3: device barrier, then unified demote decision ----
  if (tid == 0){
    __builtin_amdgcn_s_waitcnt(0);
    atomicAdd((int*)&flags[1041], 1);
    unsigned seen2 = 0; int hcap2 = 0;
    for (;;){
      seen2 = __hip_atomic_load(&flags[1041], __ATOMIC_RELAXED, __HIP_MEMORY_SCOPE_AGENT);
      if (seen2 >= 64u || ++hcap2 > HSHAKE_CAP) break;
      __builtin_amdgcn_s_sleep(8);
    }
    unsigned dm = __hip_atomic_load(&flags[1042], __ATOMIC_RELAXED, __HIP_MEMORY_SCOPE_AGENT);
    if (seen2 < 64u) dm = 1u;
    if (dm) sh_fast = 0;
  }
  __syncthreads();
  const bool fast = (sh_fast != 0);

  const int w = tid >> 6, l64 = tid & 63, l15 = tid & 15, q = (tid & 63) >> 4;
  const int fl = l15;
  const int rb0 = (l64 >> 4) * 4;            // producer row base; valid if < 8
  const bool pvalid = (l64 < 32);
  const int F0 = rank * FPW + w * 16;        // this wave's 16 output feats
  const int Fl = F0 + l15;
  const int rr = tid >> 5;                   // consumer row 0..7
  const int cc = tid & 31;                   // consumer 16-feat chunk

  // ---- weights -> registers: full K=512 for 16 feats per wave ----
  short8 wr[16], wt[16];
#pragma unroll
  for (int kc = 0; kc < 16; kc++){
    const int k = kc * 32 + q * 8;
    wr[kc] = cvt8(&W_rec[(size_t)Fl * H_DIM + k]);
    wt[kc] = cvt8(&tau_w1[(size_t)Fl * (I_DIM + H_DIM) + I_DIM + k]);
  }
  const float tw2v = tau_w2[Fl];
  const float tb2 = tau_b2_p[0];

  // ---- consumer state: h, gamma, beta in registers ----
  float h_reg[16], gamr[16], betr[16];
  {
    const int b = cl * ROWS + rr;
#pragma unroll
    for (int j = 0; j < 16; j++){
      float hv = h0[(size_t)b * H_DIM + cc * 16 + j];
      h_reg[j] = hv;
      hB[rr * HSTR + cc * 16 + j] = f2bf(hv);
      gamr[j] = gamma[cc * 16 + j];
      betr[j] = beta[cc * 16 + j];
    }
  }

  // prefetch A terms for t=0 (producer layout: 4 consecutive rows per lane)
  ushortx4 afr = (ushortx4){0,0,0,0}, atr = (ushortx4){0,0,0,0};
  if (pvalid){
    const size_t aidx = ((size_t)Fl) * BATCH + cl * ROWS + rb0;
    afr = *(const ushortx4*)&A_in[aidx];
    atr = *(const ushortx4*)&A_tau[aidx];
  }
  __syncthreads();

  for (int t = 0; t < S_LEN; t++){
    const int par = t & 1;

    // ---- producer: full-K matvec, 16 feats x 8 rows (rows 8..15 zero pad)
    floatx4 af = {0,0,0,0}, at4 = {0,0,0,0};
#pragma unroll
    for (int kc = 0; kc < 16; kc++){
      short8 ha = *(const short8*)&hB[l15 * HSTR + kc * 32 + q * 8];
      af  = __builtin_amdgcn_mfma_f32_16x16x32_bf16(ha, wr[kc], af,  0, 0, 0);
      at4 = __builtin_amdgcn_mfma_f32_16x16x32_bf16(ha, wt[kc], at4, 0, 0, 0);
    }

    // epilogue: tanh, broadcast f (packed bf16 pairs), tau partial dot
    unsigned short* bcF = bc_f + ((size_t)(par * NCL + cl) * ROWS) * H_DIM;
    float pd[4];
#pragma unroll
    for (int i2 = 0; i2 < 4; i2++){
      float vf = fast_tanh(af[i2]  + bf2f(afr[i2]));
      float vt = fast_tanh(at4[i2] + bf2f(atr[i2]));
      pd[i2] = vt * tw2v;
      unsigned pv = (unsigned)f2bf(vf);
      unsigned ov = (unsigned)__shfl_xor((int)pv, 1);
      if (pvalid && !(fl & 1)){
        unsigned short* p = bcF + (size_t)(rb0 + i2) * H_DIM + F0 + fl;
        comm_st_u32((unsigned*)p, pv | (ov << 16), fast);
      }
    }
#pragma unroll
    for (int i2 = 0; i2 < 4; i2++){
      pd[i2] += __shfl_xor(pd[i2], 1);
      pd[i2] += __shfl_xor(pd[i2], 2);
      pd[i2] += __shfl_xor(pd[i2], 4);
      pd[i2] += __shfl_xor(pd[i2], 8);
    }
    if (pvalid && fl == 0){
      float* p = bc_td + ((size_t)(par * NCL + cl) * 32 + rank * 4 + w) * ROWS + rb0;
#pragma unroll
      for (int i2 = 0; i2 < 4; i2++) comm_st_f32(p + i2, pd[i2], fast);
    }

    // drain own stores (fast: L2 ack only), then store-only arrival flag
    __builtin_amdgcn_s_waitcnt(0);
    __syncthreads();
    if (tid == 0)
      comm_st_u32(&flags[(cl * NRK + rank) << 4], (unsigned)(t + 1), fast);
    // prefetch A for t+1 — in flight during the poll wait
    if (t + 1 < S_LEN && pvalid){
      const size_t aidx = ((size_t)(t + 1) * H_DIM + Fl) * BATCH + cl * ROWS + rb0;
      afr = *(const ushortx4*)&A_in[aidx];
      atr = *(const ushortx4*)&A_tau[aidx];
    }
    if (w == 0 && l64 < NRK){
      const unsigned tgt = (unsigned)(t + 1);
      unsigned* fp = &flags[(cl * NRK + l64) << 4];
      int guard = 0;
      while (comm_ld_u32(fp, fast) < tgt){
        if (++guard > POLL_CAP) break;   // bounded: fail visibly, never hang
        __builtin_amdgcn_s_sleep(1);
      }
    }
    asm volatile("" ::: "memory");
    __syncthreads();

    // ---- consumer: readback full f slice + tau partial ----
    unsigned long long* p64 = (unsigned long long*)
      (bc_f + (((size_t)(par * NCL + cl) * ROWS) + rr) * H_DIM + cc * 16);
    float* tdp = bc_td + ((size_t)(par * NCL + cl) * 32 + cc) * ROWS + rr;
    unsigned long long v0 = comm_ld_u64(p64 + 0, fast);
    unsigned long long v1 = comm_ld_u64(p64 + 1, fast);
    unsigned long long v2 = comm_ld_u64(p64 + 2, fast);
    unsigned long long v3 = comm_ld_u64(p64 + 3, fast);
    float td = comm_ld_f32(tdp, fast);

    td += __shfl_xor(td, 1); td += __shfl_xor(td, 2);
    td += __shfl_xor(td, 4); td += __shfl_xor(td, 8);
    td += __shfl_xor(td, 16);
    const float tau = 1.0f + 9.0f * fast_sigmoid(td + tb2);
    const float c2 = 0.1f / tau, c1 = 1.0f - c2;

    float fv[16];
#pragma unroll
    for (int e = 0; e < 4; e++){
      fv[e]      = bf2f((unsigned short)(v0 >> (16 * e)));
      fv[4 + e]  = bf2f((unsigned short)(v1 >> (16 * e)));
      fv[8 + e]  = bf2f((unsigned short)(v2 >> (16 * e)));
      fv[12 + e] = bf2f((unsigned short)(v3 >> (16 * e)));
    }
    float hp[16]; float s1 = 0.f, s2 = 0.f;
#pragma unroll
    for (int j = 0; j < 16; j++){
      float v = c1 * h_reg[j] + c2 * fv[j];
      hp[j] = v; s1 += v; s2 += v * v;
    }
    s1 += __shfl_xor(s1, 1);  s2 += __shfl_xor(s2, 1);
    s1 += __shfl_xor(s1, 2);  s2 += __shfl_xor(s2, 2);
    s1 += __shfl_xor(s1, 4);  s2 += __shfl_xor(s2, 4);
    s1 += __shfl_xor(s1, 8);  s2 += __shfl_xor(s2, 8);
    s1 += __shfl_xor(s1, 16); s2 += __shfl_xor(s2, 16);
    const float mu = s1 * (1.0f / 512.0f);
    const float var = s2 * (1.0f / 512.0f) - mu * mu;
    const float rs = rsqrtf(var + 1e-5f);
#pragma unroll
    for (int j = 0; j < 16; j++) h_reg[j] = (hp[j] - mu) * rs * gamr[j] + betr[j];

    // h -> LDS bf16 for next matvec
#pragma unroll
    for (int u = 0; u < 2; u++){
      short8 hv;
#pragma unroll
      for (int e = 0; e < 8; e++) hv[e] = (short)f2bf(h_reg[u * 8 + e]);
      *(short8*)&hB[rr * HSTR + cc * 16 + u * 8] = hv;
    }

    // outputs: rank r owns batch row rr == r (each row written exactly once)
    if (rr == rank){
      float* dst = out0 + ((size_t)(cl * ROWS + rr) * S_LEN + t) * H_DIM + cc * 16;
#pragma unroll
      for (int j = 0; j < 16; j++) dst[j] = h_reg[j];
      if (cc == 0) outtau[(size_t)(cl * ROWS + rr) * S_LEN + t] = tau;
      if (t == S_LEN - 1){
        float* dh = outh + (size_t)(cl * ROWS + rr) * H_DIM + cc * 16;
#pragma unroll
        for (int j = 0; j < 16; j++) dh[j] = h_reg[j];
      }
    }
    __syncthreads();
  }
}

extern "C" void kernel_launch(void* const* d_in, const int* in_sizes, int n_in,
                              void* d_out, int out_size, void* d_ws, size_t ws_size,
                              hipStream_t stream) {
  const float* x      = (const float*)d_in[0];
  const float* h0     = (const float*)d_in[1];
  const float* W_in   = (const float*)d_in[2];
  const float* b_in   = (const float*)d_in[3];
  const float* W_rec  = (const float*)d_in[4];
  const float* tau_w1 = (const float*)d_in[5];
  const float* tau_b1 = (const float*)d_in[6];
  const float* tau_w2 = (const float*)d_in[7];
  const float* tau_b2 = (const float*)d_in[8];
  const float* gamma  = (const float*)d_in[9];
  const float* beta   = (const float*)d_in[10];

  char* ws = (char*)d_ws;
  unsigned short* A_in   = (unsigned short*)(ws);                 // 67,108,864 B
  unsigned short* A_tau  = (unsigned short*)(ws + 67108864);      // 67,108,864 B
  unsigned short* bc_f   = (unsigned short*)(ws + 134217728);     // 131,072 B
  float*          bc_td  = (float*)(ws + 134348800);              // 16,384 B
  unsigned int*   flags  = (unsigned int*)(ws + 134365184);       // 16,384 B (padded slots)
  unsigned short* Wbf    = (unsigned short*)(ws + 134381568);     // 262,144 B
  unsigned short* Tbf    = (unsigned short*)(ws + 134643712);     // 262,144 B

  float* out0   = (float*)d_out;
  float* outh   = out0 + (size_t)BATCH * S_LEN * H_DIM;           // 33,554,432
  float* outtau = outh + (size_t)BATCH * H_DIM;                   // +32,768

  hipMemsetAsync(flags, 0, 16384, stream);
  convert_weights_kernel<<<dim3(H_DIM), 256, 0, stream>>>(W_in, tau_w1, Wbf, Tbf);
  precompute_kernel<<<dim3(S_LEN), 256, 0, stream>>>(x, Wbf, Tbf, b_in, tau_b1, A_in, A_tau);
  scan_kernel<<<dim3(NCL * NRK), 256, 0, stream>>>(h0, W_rec, tau_w1, tau_w2, tau_b2, gamma, beta,
                                                   A_in, A_tau, bc_f, bc_td, flags,
                                                   out0, outh, outtau);
}

// Round 7
// 6660.905 us; speedup vs baseline: 1.0092x; 1.0092x over previous
//
#include <hip/hip_runtime.h>

#define S_LEN 1024
#define BATCH 64
#define I_DIM 256
#define H_DIM 512
#define NCLP 8     // cluster pairs: WG serves clusters c (rows 0..31) and c+8 (rows 32..63)
#define NRK 8      // ranks (WGs) per cluster, 64 feats each
#define RPC 4      // rows per cluster
#define HSTR 520   // LDS row stride (bf16) for h
#define XSTR 264   // LDS row stride (bf16) for x staging in precompute
#define POLL_CAP 20000

typedef short short8 __attribute__((ext_vector_type(8)));
typedef float floatx4 __attribute__((ext_vector_type(4)));
typedef unsigned short ushortx4 __attribute__((ext_vector_type(4)));

__device__ inline unsigned short f2bf(float x){
  unsigned u = __float_as_uint(x);
  u += 0x7fffu + ((u >> 16) & 1u);           // RNE
  return (unsigned short)(u >> 16);
}
__device__ inline float bf2f(unsigned short s){
  return __uint_as_float(((unsigned)s) << 16);
}
__device__ inline float fast_tanh(float x){
  float e = __expf(2.0f * x);                // inf-safe
  return 1.0f - 2.0f / (e + 1.0f);
}
__device__ inline float fast_sigmoid(float x){
  return 1.0f / (1.0f + __expf(-x));
}
__device__ inline short8 cvt8(const float* p){
  short8 r;
#pragma unroll
  for (int j = 0; j < 8; j++) r[j] = (short)f2bf(p[j]);
  return r;
}
// round-0/4 verified comm primitives: relaxed AGENT atomics
__device__ inline void ast_u32(unsigned* p, unsigned v){
  __hip_atomic_store(p, v, __ATOMIC_RELAXED, __HIP_MEMORY_SCOPE_AGENT);
}
__device__ inline void ast_f32(float* p, float v){
  __hip_atomic_store(p, v, __ATOMIC_RELAXED, __HIP_MEMORY_SCOPE_AGENT);
}
__device__ inline unsigned ald_u32(const unsigned* p){
  return __hip_atomic_load(p, __ATOMIC_RELAXED, __HIP_MEMORY_SCOPE_AGENT);
}
__device__ inline unsigned long long ald_u64(const unsigned long long* p){
  return __hip_atomic_load(p, __ATOMIC_RELAXED, __HIP_MEMORY_SCOPE_AGENT);
}
__device__ inline float ald_f32(const float* p){
  return __hip_atomic_load(p, __ATOMIC_RELAXED, __HIP_MEMORY_SCOPE_AGENT);
}

// ---------------------------------------------------------------------------
// Kernel W: pre-convert W_in and tau_w1[:, :256] to bf16. (unchanged)
// ---------------------------------------------------------------------------
__global__ __launch_bounds__(256) void convert_weights_kernel(
  const float* __restrict__ W_in, const float* __restrict__ tau_w1,
  unsigned short* __restrict__ Wbf, unsigned short* __restrict__ Tbf)
{
  const int f = blockIdx.x, k = threadIdx.x;
  Wbf[f * I_DIM + k] = f2bf(W_in[(size_t)f * I_DIM + k]);
  Tbf[f * I_DIM + k] = f2bf(tau_w1[(size_t)f * (I_DIM + H_DIM) + k]);
}

// ---------------------------------------------------------------------------
// Kernel P: A_in[t][F][b], A_tau[t][F][b]  (unchanged)
// ---------------------------------------------------------------------------
__global__ __launch_bounds__(256) void precompute_kernel(
  const float* __restrict__ x, const unsigned short* __restrict__ Wbf,
  const unsigned short* __restrict__ Tbf,
  const float* __restrict__ b_in, const float* __restrict__ tau_b1,
  unsigned short* __restrict__ A_in, unsigned short* __restrict__ A_tau)
{
  __shared__ unsigned short xs[BATCH * XSTR];
  const int t = blockIdx.x, tid = threadIdx.x;
  {
    const int br = tid >> 2, pp = tid & 3;
    const float* xrow = x + ((size_t)br * S_LEN + t) * I_DIM + pp * 64;
    unsigned short* drow = xs + br * XSTR + pp * 64;
#pragma unroll
    for (int c = 0; c < 16; c++){
      float4 v = *(const float4*)(xrow + c * 4);
      ushortx4 o; o[0] = f2bf(v.x); o[1] = f2bf(v.y); o[2] = f2bf(v.z); o[3] = f2bf(v.w);
      *(ushortx4*)(drow + c * 4) = o;
    }
  }
  __syncthreads();

  const int w = tid >> 6, l15 = tid & 15, q = (tid & 63) >> 4;
#pragma unroll 1
  for (int fb = 0; fb < 8; fb++){
    const int F = fb * 64 + w * 16 + l15;
    floatx4 accf[4], acct[4];
#pragma unroll
    for (int m = 0; m < 4; m++){ accf[m] = (floatx4){0,0,0,0}; acct[m] = (floatx4){0,0,0,0}; }
#pragma unroll
    for (int kc = 0; kc < 8; kc++){
      const int k0 = kc * 32 + q * 8;
      short8 bw = *(const short8*)&Wbf[F * I_DIM + k0];
      short8 bt = *(const short8*)&Tbf[F * I_DIM + k0];
#pragma unroll
      for (int m = 0; m < 4; m++){
        short8 a = *(const short8*)&xs[(m * 16 + l15) * XSTR + k0];
        accf[m] = __builtin_amdgcn_mfma_f32_16x16x32_bf16(a, bw, accf[m], 0, 0, 0);
        acct[m] = __builtin_amdgcn_mfma_f32_16x16x32_bf16(a, bt, acct[m], 0, 0, 0);
      }
    }
    const float bi = b_in[F], bt1 = tau_b1[F];
#pragma unroll
    for (int m = 0; m < 4; m++){
      ushortx4 pf, pt;
#pragma unroll
      for (int i2 = 0; i2 < 4; i2++){ pf[i2] = f2bf(accf[m][i2] + bi); pt[i2] = f2bf(acct[m][i2] + bt1); }
      const size_t base = ((size_t)t * H_DIM + F) * BATCH + m * 16 + q * 4;
      *(ushortx4*)(A_in + base) = pf;
      *(ushortx4*)(A_tau + base) = pt;
    }
  }
}

// ---------------------------------------------------------------------------
// Kernel S: persistent scan, 64 WGs x 256 thr, TWO independent recurrence
// groups per WG (rows 0..31 and 32..63). Per iteration both groups advance
// one step; group B's MFMA/epilogue fills group A's store-drain window, one
// drain + ONE flag covers both groups, both readbacks batched into one RT,
// and the two LN phases fill the readback latency. All comm = relaxed AGENT
// atomics (the only verified-fast mechanism on this chip, rounds 0-5).
// ---------------------------------------------------------------------------
__global__ __launch_bounds__(256, 1) void scan_kernel(
  const float* __restrict__ h0, const float* __restrict__ W_rec,
  const float* __restrict__ tau_w1, const float* __restrict__ tau_w2,
  const float* __restrict__ tau_b2_p, const float* __restrict__ gamma,
  const float* __restrict__ beta,
  const unsigned short* __restrict__ A_in, const unsigned short* __restrict__ A_tau,
  unsigned short* __restrict__ bc_f, float* __restrict__ bc_td,
  unsigned int* __restrict__ flags,
  float* __restrict__ out0, float* __restrict__ outh, float* __restrict__ outtau)
{
  __shared__ unsigned short hA[16 * HSTR];    // group A h (rows 0..3 real, 4..15 zero)
  __shared__ unsigned short hBs[16 * HSTR];   // group B h

  const int tid = threadIdx.x;
  const int c    = blockIdx.x & 7;     // cluster pair id
  const int rank = blockIdx.x >> 3;    // feat rank
  const int w = tid >> 6, l64 = tid & 63, l15 = l64 & 15, q = l64 >> 4;
  const int fl = l15;
  const bool pvalid = (l64 < 16);      // D rows 0..3 live in lanes 0..15
  const int F0 = rank * 64 + w * 16;   // wave's 16 feats
  const int Fl = F0 + l15;
  const int rr = w;                    // consumer: one wave per row (0..3)
  const int lane = l64;                // consumer: 8 feats per lane

  for (int idx = tid; idx < 16 * HSTR; idx += 256){ hA[idx] = 0; hBs[idx] = 0; }

  // ---- weights -> registers: full K=512 for 16 feats per wave ----
  short8 wr[16], wt[16];
#pragma unroll
  for (int kc = 0; kc < 16; kc++){
    const int k = kc * 32 + q * 8;
    wr[kc] = cvt8(&W_rec[(size_t)Fl * H_DIM + k]);
    wt[kc] = cvt8(&tau_w1[(size_t)Fl * (I_DIM + H_DIM) + I_DIM + k]);
  }
  const float tw2v = tau_w2[Fl];
  const float tb2 = tau_b2_p[0];
  __syncthreads();   // zero-fill done before h0 writes

  // ---- consumer state ----
  const int bA = c * RPC + rr;         // batch row, group A
  const int bB = 32 + c * RPC + rr;    // batch row, group B
  float h_A[8], h_B[8], gamr[8], betr[8];
#pragma unroll
  for (int j = 0; j < 8; j++){
    float va = h0[(size_t)bA * H_DIM + lane * 8 + j];
    float vb = h0[(size_t)bB * H_DIM + lane * 8 + j];
    h_A[j] = va; h_B[j] = vb;
    hA [rr * HSTR + lane * 8 + j] = f2bf(va);
    hBs[rr * HSTR + lane * 8 + j] = f2bf(vb);
    gamr[j] = gamma[lane * 8 + j];
    betr[j] = beta[lane * 8 + j];
  }

  // A prefetch t=0 (4 consecutive rows per lane)
  ushortx4 afA = (ushortx4){0,0,0,0}, atA = afA, afB = afA, atB = afA;
  if (pvalid){
    const size_t ai = ((size_t)Fl) * BATCH;
    afA = *(const ushortx4*)&A_in [ai + c * RPC];
    atA = *(const ushortx4*)&A_tau[ai + c * RPC];
    afB = *(const ushortx4*)&A_in [ai + 32 + c * RPC];
    atB = *(const ushortx4*)&A_tau[ai + 32 + c * RPC];
  }
  __syncthreads();

  for (int t = 0; t < S_LEN; t++){
    const int par = t & 1;

    // ======== produce group A ========
    {
      floatx4 af = {0,0,0,0}, at4 = {0,0,0,0};
#pragma unroll
      for (int kc = 0; kc < 16; kc++){
        short8 ha = *(const short8*)&hA[l15 * HSTR + kc * 32 + q * 8];
        af  = __builtin_amdgcn_mfma_f32_16x16x32_bf16(ha, wr[kc], af,  0, 0, 0);
        at4 = __builtin_amdgcn_mfma_f32_16x16x32_bf16(ha, wt[kc], at4, 0, 0, 0);
      }
      unsigned short* bcF = bc_f + ((size_t)(par * 16 + c) * RPC) * H_DIM;
      float pd[4];
#pragma unroll
      for (int i2 = 0; i2 < 4; i2++){
        float vf = fast_tanh(af[i2]  + bf2f(afA[i2]));
        float vt = fast_tanh(at4[i2] + bf2f(atA[i2]));
        pd[i2] = vt * tw2v;
        unsigned pv = (unsigned)f2bf(vf);
        unsigned ov = (unsigned)__shfl_xor((int)pv, 1);
        if (pvalid && !(fl & 1))
          ast_u32((unsigned*)(bcF + (size_t)i2 * H_DIM + F0 + fl), pv | (ov << 16));
      }
#pragma unroll
      for (int i2 = 0; i2 < 4; i2++){
        pd[i2] += __shfl_xor(pd[i2], 1); pd[i2] += __shfl_xor(pd[i2], 2);
        pd[i2] += __shfl_xor(pd[i2], 4); pd[i2] += __shfl_xor(pd[i2], 8);
      }
      if (pvalid && fl == 0){
        float* p = bc_td + ((size_t)(par * 16 + c) * 32 + rank * 4 + w) * RPC;
#pragma unroll
        for (int i2 = 0; i2 < 4; i2++) ast_f32(p + i2, pd[i2]);
      }
    }
    // ======== produce group B (fills A's drain window) ========
    {
      floatx4 af = {0,0,0,0}, at4 = {0,0,0,0};
#pragma unroll
      for (int kc = 0; kc < 16; kc++){
        short8 ha = *(const short8*)&hBs[l15 * HSTR + kc * 32 + q * 8];
        af  = __builtin_amdgcn_mfma_f32_16x16x32_bf16(ha, wr[kc], af,  0, 0, 0);
        at4 = __builtin_amdgcn_mfma_f32_16x16x32_bf16(ha, wt[kc], at4, 0, 0, 0);
      }
      unsigned short* bcF = bc_f + ((size_t)(par * 16 + c + 8) * RPC) * H_DIM;
      float pd[4];
#pragma unroll
      for (int i2 = 0; i2 < 4; i2++){
        float vf = fast_tanh(af[i2]  + bf2f(afB[i2]));
        float vt = fast_tanh(at4[i2] + bf2f(atB[i2]));
        pd[i2] = vt * tw2v;
        unsigned pv = (unsigned)f2bf(vf);
        unsigned ov = (unsigned)__shfl_xor((int)pv, 1);
        if (pvalid && !(fl & 1))
          ast_u32((unsigned*)(bcF + (size_t)i2 * H_DIM + F0 + fl), pv | (ov << 16));
      }
#pragma unroll
      for (int i2 = 0; i2 < 4; i2++){
        pd[i2] += __shfl_xor(pd[i2], 1); pd[i2] += __shfl_xor(pd[i2], 2);
        pd[i2] += __shfl_xor(pd[i2], 4); pd[i2] += __shfl_xor(pd[i2], 8);
      }
      if (pvalid && fl == 0){
        float* p = bc_td + ((size_t)(par * 16 + c + 8) * 32 + rank * 4 + w) * RPC;
#pragma unroll
        for (int i2 = 0; i2 < 4; i2++) ast_f32(p + i2, pd[i2]);
      }
    }

    // ---- one drain + ONE flag for both groups ----
    __builtin_amdgcn_s_waitcnt(0);
    __syncthreads();
    if (tid == 0)
      ast_u32(&flags[(c * 8 + rank) << 4], (unsigned)(t + 1));
    // prefetch A(t+1) for both groups — in flight during the poll
    if (t + 1 < S_LEN && pvalid){
      const size_t ai = ((size_t)(t + 1) * H_DIM + Fl) * BATCH;
      afA = *(const ushortx4*)&A_in [ai + c * RPC];
      atA = *(const ushortx4*)&A_tau[ai + c * RPC];
      afB = *(const ushortx4*)&A_in [ai + 32 + c * RPC];
      atB = *(const ushortx4*)&A_tau[ai + 32 + c * RPC];
    }
    if (w == 0 && l64 < NRK){
      const unsigned tgt = (unsigned)(t + 1);
      const unsigned* fp = &flags[(c * 8 + l64) << 4];
      int guard = 0;
      while (ald_u32(fp) < tgt){
        if (++guard > POLL_CAP) break;   // bounded: fail visibly, never hang
        __builtin_amdgcn_s_sleep(1);
      }
    }
    asm volatile("" ::: "memory");
    __syncthreads();

    // ---- readback both groups (6 independent loads -> ~1 RT) ----
    const unsigned long long* pA = (const unsigned long long*)
      (bc_f + (((size_t)(par * 16 + c) * RPC) + rr) * H_DIM + lane * 8);
    const unsigned long long* pB = (const unsigned long long*)
      (bc_f + (((size_t)(par * 16 + c + 8) * RPC) + rr) * H_DIM + lane * 8);
    unsigned long long a0 = ald_u64(pA + 0);
    unsigned long long a1 = ald_u64(pA + 1);
    unsigned long long b0 = ald_u64(pB + 0);
    unsigned long long b1 = ald_u64(pB + 1);
    float tdA = ald_f32(bc_td + ((size_t)(par * 16 + c)     * 32 + (lane & 31)) * RPC + rr);
    float tdB = ald_f32(bc_td + ((size_t)(par * 16 + c + 8) * 32 + (lane & 31)) * RPC + rr);

    // ---- consume group A ----
    {
      float td = tdA;
      td += __shfl_xor(td, 1); td += __shfl_xor(td, 2);
      td += __shfl_xor(td, 4); td += __shfl_xor(td, 8);
      td += __shfl_xor(td, 16);
      const float tau = 1.0f + 9.0f * fast_sigmoid(td + tb2);
      const float c2 = 0.1f / tau, c1 = 1.0f - c2;
      float fv[8];
#pragma unroll
      for (int e = 0; e < 4; e++){
        fv[e]     = bf2f((unsigned short)(a0 >> (16 * e)));
        fv[4 + e] = bf2f((unsigned short)(a1 >> (16 * e)));
      }
      float hp[8]; float s1 = 0.f, s2 = 0.f;
#pragma unroll
      for (int j = 0; j < 8; j++){
        float v = c1 * h_A[j] + c2 * fv[j];
        hp[j] = v; s1 += v; s2 += v * v;
      }
      s1 += __shfl_xor(s1, 1);  s2 += __shfl_xor(s2, 1);
      s1 += __shfl_xor(s1, 2);  s2 += __shfl_xor(s2, 2);
      s1 += __shfl_xor(s1, 4);  s2 += __shfl_xor(s2, 4);
      s1 += __shfl_xor(s1, 8);  s2 += __shfl_xor(s2, 8);
      s1 += __shfl_xor(s1, 16); s2 += __shfl_xor(s2, 16);
      s1 += __shfl_xor(s1, 32); s2 += __shfl_xor(s2, 32);
      const float mu = s1 * (1.0f / 512.0f);
      const float var = s2 * (1.0f / 512.0f) - mu * mu;
      const float rs = rsqrtf(var + 1e-5f);
      short8 hv;
#pragma unroll
      for (int j = 0; j < 8; j++){
        h_A[j] = (hp[j] - mu) * rs * gamr[j] + betr[j];
        hv[j] = (short)f2bf(h_A[j]);
      }
      *(short8*)&hA[rr * HSTR + lane * 8] = hv;
      if ((lane >> 3) == rank){
        float* dst = out0 + ((size_t)bA * S_LEN + t) * H_DIM + lane * 8;
#pragma unroll
        for (int j = 0; j < 8; j++) dst[j] = h_A[j];
      }
      if (rank == 0 && lane == 0) outtau[(size_t)bA * S_LEN + t] = tau;
      if (t == S_LEN - 1 && rank == 0){
        float* dh = outh + (size_t)bA * H_DIM + lane * 8;
#pragma unroll
        for (int j = 0; j < 8; j++) dh[j] = h_A[j];
      }
    }
    // ---- consume group B ----
    {
      float td = tdB;
      td += __shfl_xor(td, 1); td += __shfl_xor(td, 2);
      td += __shfl_xor(td, 4); td += __shfl_xor(td, 8);
      td += __shfl_xor(td, 16);
      const float tau = 1.0f + 9.0f * fast_sigmoid(td + tb2);
      const float c2 = 0.1f / tau, c1 = 1.0f - c2;
      float fv[8];
#pragma unroll
      for (int e = 0; e < 4; e++){
        fv[e]     = bf2f((unsigned short)(b0 >> (16 * e)));
        fv[4 + e] = bf2f((unsigned short)(b1 >> (16 * e)));
      }
      float hp[8]; float s1 = 0.f, s2 = 0.f;
#pragma unroll
      for (int j = 0; j < 8; j++){
        float v = c1 * h_B[j] + c2 * fv[j];
        hp[j] = v; s1 += v; s2 += v * v;
      }
      s1 += __shfl_xor(s1, 1);  s2 += __shfl_xor(s2, 1);
      s1 += __shfl_xor(s1, 2);  s2 += __shfl_xor(s2, 2);
      s1 += __shfl_xor(s1, 4);  s2 += __shfl_xor(s2, 4);
      s1 += __shfl_xor(s1, 8);  s2 += __shfl_xor(s2, 8);
      s1 += __shfl_xor(s1, 16); s2 += __shfl_xor(s2, 16);
      s1 += __shfl_xor(s1, 32); s2 += __shfl_xor(s2, 32);
      const float mu = s1 * (1.0f / 512.0f);
      const float var = s2 * (1.0f / 512.0f) - mu * mu;
      const float rs = rsqrtf(var + 1e-5f);
      short8 hv;
#pragma unroll
      for (int j = 0; j < 8; j++){
        h_B[j] = (hp[j] - mu) * rs * gamr[j] + betr[j];
        hv[j] = (short)f2bf(h_B[j]);
      }
      *(short8*)&hBs[rr * HSTR + lane * 8] = hv;
      if ((lane >> 3) == rank){
        float* dst = out0 + ((size_t)bB * S_LEN + t) * H_DIM + lane * 8;
#pragma unroll
        for (int j = 0; j < 8; j++) dst[j] = h_B[j];
      }
      if (rank == 0 && lane == 0) outtau[(size_t)bB * S_LEN + t] = tau;
      if (t == S_LEN - 1 && rank == 0){
        float* dh = outh + (size_t)bB * H_DIM + lane * 8;
#pragma unroll
        for (int j = 0; j < 8; j++) dh[j] = h_B[j];
      }
    }
    __syncthreads();
  }
}

extern "C" void kernel_launch(void* const* d_in, const int* in_sizes, int n_in,
                              void* d_out, int out_size, void* d_ws, size_t ws_size,
                              hipStream_t stream) {
  const float* x      = (const float*)d_in[0];
  const float* h0     = (const float*)d_in[1];
  const float* W_in   = (const float*)d_in[2];
  const float* b_in   = (const float*)d_in[3];
  const float* W_rec  = (const float*)d_in[4];
  const float* tau_w1 = (const float*)d_in[5];
  const float* tau_b1 = (const float*)d_in[6];
  const float* tau_w2 = (const float*)d_in[7];
  const float* tau_b2 = (const float*)d_in[8];
  const float* gamma  = (const float*)d_in[9];
  const float* beta   = (const float*)d_in[10];

  char* ws = (char*)d_ws;
  unsigned short* A_in   = (unsigned short*)(ws);                 // 67,108,864 B
  unsigned short* A_tau  = (unsigned short*)(ws + 67108864);      // 67,108,864 B
  unsigned short* bc_f   = (unsigned short*)(ws + 134217728);     // 131,072 B (2*16*4*512*2)
  float*          bc_td  = (float*)(ws + 134348800);              // 16,384 B  (2*16*32*4*4)
  unsigned int*   flags  = (unsigned int*)(ws + 134365184);       // 16,384 B (padded slots)
  unsigned short* Wbf    = (unsigned short*)(ws + 134381568);     // 262,144 B
  unsigned short* Tbf    = (unsigned short*)(ws + 134643712);     // 262,144 B

  float* out0   = (float*)d_out;
  float* outh   = out0 + (size_t)BATCH * S_LEN * H_DIM;           // 33,554,432
  float* outtau = outh + (size_t)BATCH * H_DIM;                   // +32,768

  hipMemsetAsync(flags, 0, 16384, stream);
  convert_weights_kernel<<<dim3(H_DIM), 256, 0, stream>>>(W_in, tau_w1, Wbf, Tbf);
  precompute_kernel<<<dim3(S_LEN), 256, 0, stream>>>(x, Wbf, Tbf, b_in, tau_b1, A_in, A_tau);
  scan_kernel<<<dim3(NCLP * NRK), 256, 0, stream>>>(h0, W_rec, tau_w1, tau_w2, tau_b2, gamma, beta,
                                                    A_in, A_tau, bc_f, bc_td, flags,
                                                    out0, outh, outtau);
}

// Round 8
// 3648.869 us; speedup vs baseline: 1.8422x; 1.8255x over previous
//
#include <hip/hip_runtime.h>

#define S_LEN 1024
#define BATCH 64
#define I_DIM 256
#define H_DIM 512
#define NCL 8      // clusters (8 batch rows each)
#define NRK 8      // WGs per cluster (64 feats each)
#define ROWS 8
#define FPW 64     // feats per WG (16 per wave, full K per wave)
#define HSTR 520   // LDS row stride (bf16) for h
#define XSTR 264   // LDS row stride (bf16) for x staging in precompute
#define POLL_CAP 20000

typedef short short8 __attribute__((ext_vector_type(8)));
typedef float floatx4 __attribute__((ext_vector_type(4)));
typedef unsigned short ushortx4 __attribute__((ext_vector_type(4)));

__device__ inline unsigned short f2bf(float x){
  unsigned u = __float_as_uint(x);
  u += 0x7fffu + ((u >> 16) & 1u);           // RNE
  return (unsigned short)(u >> 16);
}
__device__ inline float bf2f(unsigned short s){
  return __uint_as_float(((unsigned)s) << 16);
}
__device__ inline float fast_tanh(float x){
  float e = __expf(2.0f * x);                // inf-safe
  return 1.0f - 2.0f / (e + 1.0f);
}
__device__ inline float fast_sigmoid(float x){
  return 1.0f / (1.0f + __expf(-x));
}
__device__ inline short8 cvt8(const float* p){
  short8 r;
#pragma unroll
  for (int j = 0; j < 8; j++) r[j] = (short)f2bf(p[j]);
  return r;
}
// verified comm primitives (rounds 0/4): relaxed AGENT atomics
__device__ inline void ast_u32(unsigned* p, unsigned v){
  __hip_atomic_store(p, v, __ATOMIC_RELAXED, __HIP_MEMORY_SCOPE_AGENT);
}
__device__ inline void ast_u64(unsigned long long* p, unsigned long long v){
  __hip_atomic_store(p, v, __ATOMIC_RELAXED, __HIP_MEMORY_SCOPE_AGENT);
}
__device__ inline unsigned long long ald_u64(const unsigned long long* p){
  return __hip_atomic_load(p, __ATOMIC_RELAXED, __HIP_MEMORY_SCOPE_AGENT);
}

// ---------------------------------------------------------------------------
// Kernel W: pre-convert W_in and tau_w1[:, :256] to bf16. (unchanged)
// ---------------------------------------------------------------------------
__global__ __launch_bounds__(256) void convert_weights_kernel(
  const float* __restrict__ W_in, const float* __restrict__ tau_w1,
  unsigned short* __restrict__ Wbf, unsigned short* __restrict__ Tbf)
{
  const int f = blockIdx.x, k = threadIdx.x;
  Wbf[f * I_DIM + k] = f2bf(W_in[(size_t)f * I_DIM + k]);
  Tbf[f * I_DIM + k] = f2bf(tau_w1[(size_t)f * (I_DIM + H_DIM) + k]);
}

// ---------------------------------------------------------------------------
// Kernel P: A_in[t][F][b], A_tau[t][F][b]  (unchanged)
// ---------------------------------------------------------------------------
__global__ __launch_bounds__(256) void precompute_kernel(
  const float* __restrict__ x, const unsigned short* __restrict__ Wbf,
  const unsigned short* __restrict__ Tbf,
  const float* __restrict__ b_in, const float* __restrict__ tau_b1,
  unsigned short* __restrict__ A_in, unsigned short* __restrict__ A_tau)
{
  __shared__ unsigned short xs[BATCH * XSTR];
  const int t = blockIdx.x, tid = threadIdx.x;
  {
    const int br = tid >> 2, pp = tid & 3;
    const float* xrow = x + ((size_t)br * S_LEN + t) * I_DIM + pp * 64;
    unsigned short* drow = xs + br * XSTR + pp * 64;
#pragma unroll
    for (int c = 0; c < 16; c++){
      float4 v = *(const float4*)(xrow + c * 4);
      ushortx4 o; o[0] = f2bf(v.x); o[1] = f2bf(v.y); o[2] = f2bf(v.z); o[3] = f2bf(v.w);
      *(ushortx4*)(drow + c * 4) = o;
    }
  }
  __syncthreads();

  const int w = tid >> 6, l15 = tid & 15, q = (tid & 63) >> 4;
#pragma unroll 1
  for (int fb = 0; fb < 8; fb++){
    const int F = fb * 64 + w * 16 + l15;
    floatx4 accf[4], acct[4];
#pragma unroll
    for (int m = 0; m < 4; m++){ accf[m] = (floatx4){0,0,0,0}; acct[m] = (floatx4){0,0,0,0}; }
#pragma unroll
    for (int kc = 0; kc < 8; kc++){
      const int k0 = kc * 32 + q * 8;
      short8 bw = *(const short8*)&Wbf[F * I_DIM + k0];
      short8 bt = *(const short8*)&Tbf[F * I_DIM + k0];
#pragma unroll
      for (int m = 0; m < 4; m++){
        short8 a = *(const short8*)&xs[(m * 16 + l15) * XSTR + k0];
        accf[m] = __builtin_amdgcn_mfma_f32_16x16x32_bf16(a, bw, accf[m], 0, 0, 0);
        acct[m] = __builtin_amdgcn_mfma_f32_16x16x32_bf16(a, bt, acct[m], 0, 0, 0);
      }
    }
    const float bi = b_in[F], bt1 = tau_b1[F];
#pragma unroll
    for (int m = 0; m < 4; m++){
      ushortx4 pf, pt;
#pragma unroll
      for (int i2 = 0; i2 < 4; i2++){ pf[i2] = f2bf(accf[m][i2] + bi); pt[i2] = f2bf(acct[m][i2] + bt1); }
      const size_t base = ((size_t)t * H_DIM + F) * BATCH + m * 16 + q * 4;
      *(ushortx4*)(A_in + base) = pf;
      *(ushortx4*)(A_tau + base) = pt;
    }
  }
}

// ---------------------------------------------------------------------------
// Kernel S: persistent scan, 64 WGs x 256 thr (round-4 structure), with the
// flag indirection replaced by per-producer-wave DATA+TAG publication:
//   producer wave: bc_f stores -> s_waitcnt(0) [own stores acked at coherence
//   point] -> store u64 {tau-partial, tag=t+1} per row.
//   consumer lane (row rr, chunk cc): polls ITS producer wave's tag entry
//   (entry cc <-> rank cc>>2, wave cc&3, feats [16cc,16cc+16)); tag arrival
//   guarantees that wave's bc_f visibility. Removes one barrier, the flag
//   store RT, and the 8-flag fan from the per-step critical chain.
// bc_tag layout: [par][cl][entry 0..31][row 0..7] u64 = 32 KB, memset/launch.
// ---------------------------------------------------------------------------
__global__ __launch_bounds__(256, 1) void scan_kernel(
  const float* __restrict__ h0, const float* __restrict__ W_rec,
  const float* __restrict__ tau_w1, const float* __restrict__ tau_w2,
  const float* __restrict__ tau_b2_p, const float* __restrict__ gamma,
  const float* __restrict__ beta,
  const unsigned short* __restrict__ A_in, const unsigned short* __restrict__ A_tau,
  unsigned short* __restrict__ bc_f, unsigned long long* __restrict__ bc_tag,
  float* __restrict__ out0, float* __restrict__ outh, float* __restrict__ outtau)
{
  __shared__ unsigned short hB[16 * HSTR];   // rows 8..15 stay zero (MFMA M=16 pad)

  const int tid = threadIdx.x;
  const int cl   = blockIdx.x & (NCL - 1);
  const int rank = blockIdx.x >> 3;

  for (int idx = tid; idx < 16 * HSTR; idx += 256) hB[idx] = 0;

  const int w = tid >> 6, l64 = tid & 63, l15 = tid & 15, q = (tid & 63) >> 4;
  const int fl = l15;
  const int rb0 = (l64 >> 4) * 4;            // producer row base; valid if < 8
  const bool pvalid = (l64 < 32);
  const int F0 = rank * FPW + w * 16;        // this wave's 16 output feats
  const int Fl = F0 + l15;
  const int rr = tid >> 5;                   // consumer row 0..7
  const int cc = tid & 31;                   // consumer 16-feat chunk

  // ---- weights -> registers: full K=512 for 16 feats per wave ----
  short8 wr[16], wt[16];
#pragma unroll
  for (int kc = 0; kc < 16; kc++){
    const int k = kc * 32 + q * 8;
    wr[kc] = cvt8(&W_rec[(size_t)Fl * H_DIM + k]);
    wt[kc] = cvt8(&tau_w1[(size_t)Fl * (I_DIM + H_DIM) + I_DIM + k]);
  }
  const float tw2v = tau_w2[Fl];
  const float tb2 = tau_b2_p[0];
  __syncthreads();   // hB zero-init done before h0 fill

  // ---- consumer state: h, gamma, beta in registers ----
  float h_reg[16], gamr[16], betr[16];
  {
    const int b = cl * ROWS + rr;
#pragma unroll
    for (int j = 0; j < 16; j++){
      float hv = h0[(size_t)b * H_DIM + cc * 16 + j];
      h_reg[j] = hv;
      hB[rr * HSTR + cc * 16 + j] = f2bf(hv);
      gamr[j] = gamma[cc * 16 + j];
      betr[j] = beta[cc * 16 + j];
    }
  }

  // prefetch A terms for t=0 (producer layout: 4 consecutive rows per lane)
  ushortx4 afr = (ushortx4){0,0,0,0}, atr = (ushortx4){0,0,0,0};
  if (pvalid){
    const size_t aidx = ((size_t)Fl) * BATCH + cl * ROWS + rb0;
    afr = *(const ushortx4*)&A_in[aidx];
    atr = *(const ushortx4*)&A_tau[aidx];
  }
  __syncthreads();

  for (int t = 0; t < S_LEN; t++){
    const int par = t & 1;

    // ---- producer: full-K matvec, 16 feats x 8 rows (rows 8..15 zero pad)
    floatx4 af = {0,0,0,0}, at4 = {0,0,0,0};
#pragma unroll
    for (int kc = 0; kc < 16; kc++){
      short8 ha = *(const short8*)&hB[l15 * HSTR + kc * 32 + q * 8];
      af  = __builtin_amdgcn_mfma_f32_16x16x32_bf16(ha, wr[kc], af,  0, 0, 0);
      at4 = __builtin_amdgcn_mfma_f32_16x16x32_bf16(ha, wt[kc], at4, 0, 0, 0);
    }

    // epilogue: tanh, broadcast f (packed bf16 pairs), tau partial dot
    unsigned short* bcF = bc_f + ((size_t)(par * NCL + cl) * ROWS) * H_DIM;
    float pd[4];
#pragma unroll
    for (int i2 = 0; i2 < 4; i2++){
      float vf = fast_tanh(af[i2]  + bf2f(afr[i2]));
      float vt = fast_tanh(at4[i2] + bf2f(atr[i2]));
      pd[i2] = vt * tw2v;
      unsigned pv = (unsigned)f2bf(vf);
      unsigned ov = (unsigned)__shfl_xor((int)pv, 1);
      if (pvalid && !(fl & 1)){
        unsigned short* p = bcF + (size_t)(rb0 + i2) * H_DIM + F0 + fl;
        ast_u32((unsigned*)p, pv | (ov << 16));
      }
    }
#pragma unroll
    for (int i2 = 0; i2 < 4; i2++){
      pd[i2] += __shfl_xor(pd[i2], 1);
      pd[i2] += __shfl_xor(pd[i2], 2);
      pd[i2] += __shfl_xor(pd[i2], 4);
      pd[i2] += __shfl_xor(pd[i2], 8);
    }

    // per-wave drain of own bc_f stores, then publish {tau-partial, tag}
    __builtin_amdgcn_s_waitcnt(0);
    asm volatile("" ::: "memory");
    if (pvalid && fl == 0){
      unsigned long long* tp =
        bc_tag + (((size_t)(par * NCL + cl)) * 32 + rank * 4 + w) * 8 + rb0;
      const unsigned long long tag = ((unsigned long long)(t + 1)) << 32;
#pragma unroll
      for (int i2 = 0; i2 < 4; i2++)
        ast_u64(tp + i2, tag | (unsigned long long)__float_as_uint(pd[i2]));
    }
    // prefetch A for t+1 — in flight during the poll
    if (t + 1 < S_LEN && pvalid){
      const size_t aidx = ((size_t)(t + 1) * H_DIM + Fl) * BATCH + cl * ROWS + rb0;
      afr = *(const ushortx4*)&A_in[aidx];
      atr = *(const ushortx4*)&A_tau[aidx];
    }
    __syncthreads();   // all hB reads done before consumer hB writes

    // ---- consumer: poll OWN producer wave's tag (value rides along) ----
    const unsigned long long* tp =
      bc_tag + (((size_t)(par * NCL + cl)) * 32 + cc) * 8 + rr;
    unsigned long long tv; int guard = 0;
    const unsigned tgt = (unsigned)(t + 1);
    for (;;){
      tv = ald_u64(tp);
      if ((unsigned)(tv >> 32) >= tgt || ++guard > POLL_CAP) break;
      __builtin_amdgcn_s_sleep(1);
    }
    asm volatile("" ::: "memory");
    float td = __uint_as_float((unsigned)tv);

    // readback f slice (producer wave for chunk cc has drained before tag)
    const unsigned long long* p64 = (const unsigned long long*)
      (bc_f + (((size_t)(par * NCL + cl) * ROWS) + rr) * H_DIM + cc * 16);
    unsigned long long v0 = ald_u64(p64 + 0);
    unsigned long long v1 = ald_u64(p64 + 1);
    unsigned long long v2 = ald_u64(p64 + 2);
    unsigned long long v3 = ald_u64(p64 + 3);

    td += __shfl_xor(td, 1); td += __shfl_xor(td, 2);
    td += __shfl_xor(td, 4); td += __shfl_xor(td, 8);
    td += __shfl_xor(td, 16);
    const float tau = 1.0f + 9.0f * fast_sigmoid(td + tb2);
    const float c2 = 0.1f / tau, c1 = 1.0f - c2;

    float fv[16];
#pragma unroll
    for (int e = 0; e < 4; e++){
      fv[e]      = bf2f((unsigned short)(v0 >> (16 * e)));
      fv[4 + e]  = bf2f((unsigned short)(v1 >> (16 * e)));
      fv[8 + e]  = bf2f((unsigned short)(v2 >> (16 * e)));
      fv[12 + e] = bf2f((unsigned short)(v3 >> (16 * e)));
    }
    float hp[16]; float s1 = 0.f, s2 = 0.f;
#pragma unroll
    for (int j = 0; j < 16; j++){
      float v = c1 * h_reg[j] + c2 * fv[j];
      hp[j] = v; s1 += v; s2 += v * v;
    }
    s1 += __shfl_xor(s1, 1);  s2 += __shfl_xor(s2, 1);
    s1 += __shfl_xor(s1, 2);  s2 += __shfl_xor(s2, 2);
    s1 += __shfl_xor(s1, 4);  s2 += __shfl_xor(s2, 4);
    s1 += __shfl_xor(s1, 8);  s2 += __shfl_xor(s2, 8);
    s1 += __shfl_xor(s1, 16); s2 += __shfl_xor(s2, 16);
    const float mu = s1 * (1.0f / 512.0f);
    const float var = s2 * (1.0f / 512.0f) - mu * mu;
    const float rs = rsqrtf(var + 1e-5f);
#pragma unroll
    for (int j = 0; j < 16; j++) h_reg[j] = (hp[j] - mu) * rs * gamr[j] + betr[j];

    // h -> LDS bf16 for next matvec
#pragma unroll
    for (int u = 0; u < 2; u++){
      short8 hv;
#pragma unroll
      for (int e = 0; e < 8; e++) hv[e] = (short)f2bf(h_reg[u * 8 + e]);
      *(short8*)&hB[rr * HSTR + cc * 16 + u * 8] = hv;
    }

    // outputs: rank r owns batch row rr == r (each row written exactly once)
    if (rr == rank){
      float* dst = out0 + ((size_t)(cl * ROWS + rr) * S_LEN + t) * H_DIM + cc * 16;
#pragma unroll
      for (int j = 0; j < 16; j++) dst[j] = h_reg[j];
      if (cc == 0) outtau[(size_t)(cl * ROWS + rr) * S_LEN + t] = tau;
      if (t == S_LEN - 1){
        float* dh = outh + (size_t)(cl * ROWS + rr) * H_DIM + cc * 16;
#pragma unroll
        for (int j = 0; j < 16; j++) dh[j] = h_reg[j];
      }
    }
    __syncthreads();
  }
}

extern "C" void kernel_launch(void* const* d_in, const int* in_sizes, int n_in,
                              void* d_out, int out_size, void* d_ws, size_t ws_size,
                              hipStream_t stream) {
  const float* x      = (const float*)d_in[0];
  const float* h0     = (const float*)d_in[1];
  const float* W_in   = (const float*)d_in[2];
  const float* b_in   = (const float*)d_in[3];
  const float* W_rec  = (const float*)d_in[4];
  const float* tau_w1 = (const float*)d_in[5];
  const float* tau_b1 = (const float*)d_in[6];
  const float* tau_w2 = (const float*)d_in[7];
  const float* tau_b2 = (const float*)d_in[8];
  const float* gamma  = (const float*)d_in[9];
  const float* beta   = (const float*)d_in[10];

  char* ws = (char*)d_ws;
  unsigned short*     A_in   = (unsigned short*)(ws);                 // 67,108,864 B
  unsigned short*     A_tau  = (unsigned short*)(ws + 67108864);      // 67,108,864 B
  unsigned short*     bc_f   = (unsigned short*)(ws + 134217728);     // 131,072 B
  unsigned long long* bc_tag = (unsigned long long*)(ws + 134348800); // 32,768 B (2*8*32*8 u64)
  unsigned short*     Wbf    = (unsigned short*)(ws + 134381568);     // 262,144 B
  unsigned short*     Tbf    = (unsigned short*)(ws + 134643712);     // 262,144 B

  float* out0   = (float*)d_out;
  float* outh   = out0 + (size_t)BATCH * S_LEN * H_DIM;               // 33,554,432
  float* outtau = outh + (size_t)BATCH * H_DIM;                       // +32,768

  hipMemsetAsync(bc_tag, 0, 32768, stream);   // tags persist across graph replays
  convert_weights_kernel<<<dim3(H_DIM), 256, 0, stream>>>(W_in, tau_w1, Wbf, Tbf);
  precompute_kernel<<<dim3(S_LEN), 256, 0, stream>>>(x, Wbf, Tbf, b_in, tau_b1, A_in, A_tau);
  scan_kernel<<<dim3(NCL * NRK), 256, 0, stream>>>(h0, W_rec, tau_w1, tau_w2, tau_b2, gamma, beta,
                                                   A_in, A_tau, bc_f, bc_tag,
                                                   out0, outh, outtau);
}